// Round 10
// baseline (365.072 us; speedup 1.0000x reference)
//
#include <hip/hip_runtime.h>
#include <hip/hip_fp16.h>

#define N_NODES 50000
#define N_EDGES 800000
#define HID 128
#define OUT_CH 64
#define NB_SCAN 196   // ceil(50000/256)

// ---------------- CSR construction ----------------

__global__ void prep_init(int* __restrict__ counts, float* __restrict__ sum) {
    int i = blockIdx.x * blockDim.x + threadIdx.x;
    if (i < N_NODES) counts[i] = 0;
    if (i < OUT_CH) sum[i] = 0.0f;
}

__global__ void count_edges(const int* __restrict__ ei, int* __restrict__ counts) {
    int e = blockIdx.x * blockDim.x + threadIdx.x;
    if (e < N_EDGES) atomicAdd(&counts[ei[N_EDGES + e]], 1);  // target
}

__global__ __launch_bounds__(256)
void scan_blocks(const int* __restrict__ counts, int* __restrict__ row_start,
                 int* __restrict__ bsum) {
    __shared__ int s[256];
    int tid = threadIdx.x;
    int i = blockIdx.x * 256 + tid;
    int v = (i < N_NODES) ? counts[i] : 0;
    s[tid] = v;
    __syncthreads();
    for (int off = 1; off < 256; off <<= 1) {
        int t = (tid >= off) ? s[tid - off] : 0;
        __syncthreads();
        s[tid] += t;
        __syncthreads();
    }
    if (i < N_NODES) row_start[i] = s[tid] - v;  // exclusive
    if (tid == 255) bsum[blockIdx.x] = s[255];
}

__global__ __launch_bounds__(256)
void scan_bsums(int* __restrict__ bsum) {
    __shared__ int s[256];
    int tid = threadIdx.x;
    int v = (tid < NB_SCAN) ? bsum[tid] : 0;
    s[tid] = v;
    __syncthreads();
    for (int off = 1; off < 256; off <<= 1) {
        int t = (tid >= off) ? s[tid - off] : 0;
        __syncthreads();
        s[tid] += t;
        __syncthreads();
    }
    if (tid < NB_SCAN) bsum[tid] = s[tid] - v;  // exclusive
}

__global__ void scan_fixup(int* __restrict__ row_start, const int* __restrict__ bsum,
                           int* __restrict__ cursor, const int* __restrict__ counts,
                           float* __restrict__ dinv) {
    int i = blockIdx.x * blockDim.x + threadIdx.x;
    if (i < N_NODES) {
        int rs = row_start[i] + bsum[i >> 8];
        row_start[i] = rs;
        cursor[i] = rs;
        dinv[i] = rsqrtf(1.0f + (float)counts[i]);  // +1 self-loop
    }
    if (i == 0) row_start[N_NODES] = N_EDGES;
}

// destination-sorted source list (weights folded into features via dinv pre-scale)
__global__ void csr_fill(const int* __restrict__ ei, int* __restrict__ cursor,
                         int* __restrict__ esrc) {
    int e = blockIdx.x * blockDim.x + threadIdx.x;
    if (e < N_EDGES) {
        int r = ei[e];
        int c = ei[N_EDGES + e];
        int pos = atomicAdd(&cursor[c], 1);
        esrc[pos] = r;
    }
}

// ---------------- register-tiled GEMM: Y[n][OUT] = X[n][128] @ W[128][OUT] ----------------
// ROWS-row x OUT-col tile per 256-thread block; K staged in 32-wide chunks.
// SCALE: multiply row r by dinv[r] in epilogue (pre-scales features for aggregation).
// HALF_OUT: write fp16, else fp32.

template <int OUT, bool ADD_BIAS, bool HALF_OUT, bool SCALE>
__global__ __launch_bounds__(256)
void gemm_rt(const float* __restrict__ X, const float* __restrict__ W,
             const float* __restrict__ bias, const float* __restrict__ dinv,
             void* __restrict__ Yv, int n) {
    constexpr int CG   = OUT / 4;              // col groups (32 or 16)
    constexpr int RG   = 256 / CG;             // row groups (8 or 16)
    constexpr int ROWS = (OUT == 128) ? 32 : 64;
    constexpr int PR   = ROWS / RG;            // 4 rows per thread
    constexpr int XLD  = ROWS + 4;             // padded LDS stride (mult of 4)

    __shared__ __align__(16) float Wl[32 * OUT];
    __shared__ __align__(16) float XlT[32 * XLD];

    const int tid = threadIdx.x;
    const int cx = tid % CG;
    const int ry = tid / CG;
    const int r0 = blockIdx.x * ROWS;

    float4 acc[PR];
#pragma unroll
    for (int j = 0; j < PR; j++) acc[j] = make_float4(0.f, 0.f, 0.f, 0.f);

    for (int k0 = 0; k0 < 128; k0 += 32) {
        __syncthreads();
        for (int t = tid; t < 32 * OUT; t += 256) Wl[t] = W[k0 * OUT + t];
        for (int t = tid; t < ROWS * 32; t += 256) {
            int r = t >> 5, kk = t & 31;
            XlT[kk * XLD + r] =
                (r0 + r < n) ? X[(size_t)(r0 + r) * 128 + k0 + kk] : 0.0f;
        }
        __syncthreads();

#pragma unroll
        for (int kk = 0; kk < 32; kk++) {
            const float4 w = *(const float4*)&Wl[kk * OUT + cx * 4];
            const float4 xq = *(const float4*)&XlT[kk * XLD + ry * 4];
            float xv[4] = {xq.x, xq.y, xq.z, xq.w};
#pragma unroll
            for (int j = 0; j < PR; j++) {
                acc[j].x += xv[j] * w.x;
                acc[j].y += xv[j] * w.y;
                acc[j].z += xv[j] * w.z;
                acc[j].w += xv[j] * w.w;
            }
        }
    }

    float4 bv = make_float4(0.f, 0.f, 0.f, 0.f);
    if (ADD_BIAS) bv = *(const float4*)&bias[cx * 4];
#pragma unroll
    for (int j = 0; j < PR; j++) {
        int r = r0 + ry * PR + j;
        if (r < n) {
            float4 o;
            o.x = acc[j].x + bv.x;
            o.y = acc[j].y + bv.y;
            o.z = acc[j].z + bv.z;
            o.w = acc[j].w + bv.w;
            if constexpr (SCALE) {
                float dr = dinv[r];
                o.x *= dr; o.y *= dr; o.z *= dr; o.w *= dr;
            }
            if constexpr (HALF_OUT) {
                union { __half2 h2[2]; int2 i2; } u;
                u.h2[0] = __floats2half2_rn(o.x, o.y);
                u.h2[1] = __floats2half2_rn(o.z, o.w);
                *(int2*)((__half*)Yv + (size_t)r * OUT + cx * 4) = u.i2;
            } else {
                *(float4*)((float*)Yv + (size_t)r * OUT + cx * 4) = o;
            }
        }
    }
}

// ---------------- fused aggregation ----------------
// t is dinv-pre-scaled fp16. out[c] = dinv[c]*(t[c] + sum_{src} t[src]) + b, relu.
// One node per 32 lanes, 4 fp16 features (int2 = 8B) per lane; f32 accumulate.

__global__ __launch_bounds__(256)
void aggregate_h(const __half* __restrict__ t, const int* __restrict__ row_start,
                 const int* __restrict__ esrc, const float* __restrict__ dinv,
                 const float* __restrict__ bias, float* __restrict__ out) {
    const int tid = threadIdx.x;
    const int node = blockIdx.x * 8 + (tid >> 5);
    const int f4 = tid & 31;   // features 4*f4 .. 4*f4+3
    if (node >= N_NODES) return;

    const int2* t2 = (const int2*)t;

    int2 sg = t2[(size_t)node * 32 + f4];       // t_scaled[node] (self term)
    float2 slo = __half22float2(*(__half2*)&sg.x);
    float2 shi = __half22float2(*(__half2*)&sg.y);
    float4 acc = make_float4(slo.x, slo.y, shi.x, shi.y);

    int k = row_start[node];
    const int k1 = row_start[node + 1];
    for (; k + 8 <= k1; k += 8) {
        int src[8];
#pragma unroll
        for (int u = 0; u < 8; u++) src[u] = esrc[k + u];
        int2 g[8];
#pragma unroll
        for (int u = 0; u < 8; u++) g[u] = t2[(size_t)src[u] * 32 + f4];
#pragma unroll
        for (int u = 0; u < 8; u++) {
            float2 lo = __half22float2(*(__half2*)&g[u].x);
            float2 hi = __half22float2(*(__half2*)&g[u].y);
            acc.x += lo.x;
            acc.y += lo.y;
            acc.z += hi.x;
            acc.w += hi.y;
        }
    }
    for (; k < k1; k++) {
        int2 g = t2[(size_t)esrc[k] * 32 + f4];
        float2 lo = __half22float2(*(__half2*)&g.x);
        float2 hi = __half22float2(*(__half2*)&g.y);
        acc.x += lo.x;
        acc.y += lo.y;
        acc.z += hi.x;
        acc.w += hi.y;
    }

    const float d = dinv[node];
    float4 b = ((const float4*)bias)[f4];
    acc.x = fmaxf(acc.x * d + b.x, 0.f);
    acc.y = fmaxf(acc.y * d + b.y, 0.f);
    acc.z = fmaxf(acc.z * d + b.z, 0.f);
    acc.w = fmaxf(acc.w * d + b.w, 0.f);
    ((float4*)out)[(size_t)node * 32 + f4] = acc;
}

// ---------------- mean pool ----------------

__global__ __launch_bounds__(256)
void mean_partial(const float* __restrict__ P, float* __restrict__ sum) {
    __shared__ float red[256];
    const int tid = threadIdx.x;
    const int c = tid & 63;
    const int grp = tid >> 6;
    float acc = 0.0f;
    for (int r = blockIdx.x * 4 + grp; r < N_NODES; r += gridDim.x * 4)
        acc += P[r * OUT_CH + c];
    red[tid] = acc;
    __syncthreads();
    if (grp == 0) {
        float s = red[c] + red[64 + c] + red[128 + c] + red[192 + c];
        atomicAdd(&sum[c], s);
    }
}

__global__ void mean_final(const float* __restrict__ sum, float* __restrict__ out) {
    int j = threadIdx.x;
    if (j < OUT_CH) out[N_NODES * OUT_CH + j] = sum[j] * (1.0f / N_NODES);
}

// ---------------- launch ----------------

extern "C" void kernel_launch(void* const* d_in, const int* in_sizes, int n_in,
                              void* d_out, int out_size, void* d_ws, size_t ws_size,
                              hipStream_t stream) {
    const float* x  = (const float*)d_in[0];
    const int* ei   = (const int*)d_in[1];   // int32 on device
    const float* W1 = (const float*)d_in[2];
    const float* b1 = (const float*)d_in[3];
    const float* W2 = (const float*)d_in[4];
    const float* b2 = (const float*)d_in[5];
    const float* W3 = (const float*)d_in[6];
    const float* b3 = (const float*)d_in[7];
    const float* Wo = (const float*)d_in[8];
    const float* bo = (const float*)d_in[9];
    float* out = (float*)d_out;

    char* ws = (char*)d_ws;
    auto take = [&](size_t bytes) {
        char* p = ws;
        ws += (bytes + 255) & ~size_t(255);
        return (void*)p;
    };
    int*    counts    = (int*)take((size_t)N_NODES * 4);
    int*    row_start = (int*)take((size_t)(N_NODES + 1) * 4);
    int*    bsum      = (int*)take((size_t)NB_SCAN * 4);
    int*    cursor    = (int*)take((size_t)N_NODES * 4);
    float*  dinv      = (float*)take((size_t)N_NODES * 4);
    int*    esrc      = (int*)take((size_t)N_EDGES * 4);
    float*  sum       = (float*)take(OUT_CH * 4);
    __half* hA        = (__half*)take((size_t)N_NODES * HID * 2);
    float*  hB        = (float*)take((size_t)N_NODES * HID * 4);

    const int BS = 256;
    const int gN      = (N_NODES + BS - 1) / BS;
    const int gE      = (N_EDGES + BS - 1) / BS;
    const int gGemmH  = (N_NODES + 31) / 32;   // 32-row tiles for OUT=128
    const int gGemmO  = (N_NODES + 63) / 64;   // 64-row tiles for OUT=64
    const int gAgg    = (N_NODES + 7) / 8;

    // CSR build
    prep_init<<<gN, BS, 0, stream>>>(counts, sum);
    count_edges<<<gE, BS, 0, stream>>>(ei, counts);
    scan_blocks<<<NB_SCAN, BS, 0, stream>>>(counts, row_start, bsum);
    scan_bsums<<<1, BS, 0, stream>>>(bsum);
    scan_fixup<<<gN, BS, 0, stream>>>(row_start, bsum, cursor, counts, dinv);
    csr_fill<<<gE, BS, 0, stream>>>(ei, cursor, esrc);

    const float* hin = x;
    const float* Ws[3] = {W1, W2, W3};
    const float* bs[3] = {b1, b2, b3};
    for (int layer = 0; layer < 3; layer++) {
        gemm_rt<HID, false, true, true><<<gGemmH, BS, 0, stream>>>(
            hin, Ws[layer], nullptr, dinv, hA, N_NODES);
        aggregate_h<<<gAgg, BS, 0, stream>>>(hA, row_start, esrc, dinv, bs[layer], hB);
        hin = hB;
    }

    gemm_rt<OUT_CH, true, false, false><<<gGemmO, BS, 0, stream>>>(
        hB, Wo, bo, nullptr, out, N_NODES);
    mean_partial<<<256, BS, 0, stream>>>(out, sum);
    mean_final<<<1, 64, 0, stream>>>(sum, out);
}

// Round 11
// 315.862 us; speedup vs baseline: 1.1558x; 1.1558x over previous
//
#include <hip/hip_runtime.h>
#include <hip/hip_fp16.h>

#define N_NODES 50000
#define N_EDGES 800000
#define HID 128
#define OUT_CH 64
#define NB_SCAN 196   // ceil(50000/256)

typedef __attribute__((ext_vector_type(8))) _Float16 half8;
typedef __attribute__((ext_vector_type(4))) float floatx4;

// ---------------- CSR construction ----------------

__global__ void prep_init(int* __restrict__ counts, float* __restrict__ sum) {
    int i = blockIdx.x * blockDim.x + threadIdx.x;
    if (i < N_NODES) counts[i] = 0;
    if (i < OUT_CH) sum[i] = 0.0f;
}

__global__ void count_edges(const int* __restrict__ ei, int* __restrict__ counts) {
    int e = blockIdx.x * blockDim.x + threadIdx.x;
    if (e < N_EDGES) atomicAdd(&counts[ei[N_EDGES + e]], 1);  // target
}

__global__ __launch_bounds__(256)
void scan_blocks(const int* __restrict__ counts, int* __restrict__ row_start,
                 int* __restrict__ bsum) {
    __shared__ int s[256];
    int tid = threadIdx.x;
    int i = blockIdx.x * 256 + tid;
    int v = (i < N_NODES) ? counts[i] : 0;
    s[tid] = v;
    __syncthreads();
    for (int off = 1; off < 256; off <<= 1) {
        int t = (tid >= off) ? s[tid - off] : 0;
        __syncthreads();
        s[tid] += t;
        __syncthreads();
    }
    if (i < N_NODES) row_start[i] = s[tid] - v;  // exclusive
    if (tid == 255) bsum[blockIdx.x] = s[255];
}

__global__ __launch_bounds__(256)
void scan_bsums(int* __restrict__ bsum) {
    __shared__ int s[256];
    int tid = threadIdx.x;
    int v = (tid < NB_SCAN) ? bsum[tid] : 0;
    s[tid] = v;
    __syncthreads();
    for (int off = 1; off < 256; off <<= 1) {
        int t = (tid >= off) ? s[tid - off] : 0;
        __syncthreads();
        s[tid] += t;
        __syncthreads();
    }
    if (tid < NB_SCAN) bsum[tid] = s[tid] - v;  // exclusive
}

__global__ void scan_fixup(int* __restrict__ row_start, const int* __restrict__ bsum,
                           int* __restrict__ cursor, const int* __restrict__ counts,
                           float* __restrict__ dinv) {
    int i = blockIdx.x * blockDim.x + threadIdx.x;
    if (i < N_NODES) {
        int rs = row_start[i] + bsum[i >> 8];
        row_start[i] = rs;
        cursor[i] = rs;
        dinv[i] = rsqrtf(1.0f + (float)counts[i]);  // +1 self-loop
    }
    if (i == 0) row_start[N_NODES] = N_EDGES;
}

__global__ void csr_fill(const int* __restrict__ ei, int* __restrict__ cursor,
                         int* __restrict__ esrc) {
    int e = blockIdx.x * blockDim.x + threadIdx.x;
    if (e < N_EDGES) {
        int r = ei[e];
        int c = ei[N_EDGES + e];
        int pos = atomicAdd(&cursor[c], 1);
        esrc[pos] = r;
    }
}

// ---------------- fp16 prep ----------------

__global__ void convert_x(const float* __restrict__ x, _Float16* __restrict__ xh) {
    int i = blockIdx.x * 256 + threadIdx.x;   // one float4 per thread
    if (i < N_NODES * (HID / 4)) {
        float4 v = ((const float4*)x)[i];
        union { __half2 h2[2]; int2 i2; } u;
        u.h2[0] = __floats2half2_rn(v.x, v.y);
        u.h2[1] = __floats2half2_rn(v.z, v.w);
        ((int2*)xh)[i] = u.i2;
    }
}

// Wt[c][k] = (fp16) W[k][c]
__global__ void wtrans(const float* __restrict__ W, _Float16* __restrict__ Wt,
                       int K, int N) {
    int i = blockIdx.x * 256 + threadIdx.x;
    if (i < K * N) {
        int k = i / N, c = i - k * N;
        Wt[(size_t)c * K + k] = (_Float16)W[i];
    }
}

// ---------------- MFMA GEMM: Y[n][OUT] = A(fp16)[n][128] @ W, Wt is [OUT][128] ----------------
// Wave = 16 rows x 64 cols (4 16x16 tiles, K=128 -> 4 MFMA each). No LDS, no syncs.
// Fragment layouts (verified m89/m92): A row=lane&15, k=(lane>>4)*8+e (16B contig);
// B col=lane&15, same k; D col=lane&15, row=(lane>>4)*4+r.

template <int OUT, bool ADD_BIAS, bool SCALE, bool HALF_OUT>
__global__ __launch_bounds__(256)
void gemm_mfma(const _Float16* __restrict__ A, const _Float16* __restrict__ Wt,
               const float* __restrict__ bias, const float* __restrict__ dinv,
               void* __restrict__ Yv, int n) {
    const int tid  = threadIdx.x;
    const int lane = tid & 63;
    const int wv   = tid >> 6;
    const int m0   = blockIdx.x * 64 + wv * 16;
    if (m0 >= n) return;                       // n % 16 == 0: no partial bands
    const int l15  = lane & 15;
    const int kb   = lane >> 4;                // 0..3
    const int col0 = blockIdx.y * 64;

    const _Float16* arow = A + (size_t)(m0 + l15) * 128 + kb * 8;
    half8 a[4];
#pragma unroll
    for (int j = 0; j < 4; j++) a[j] = *(const half8*)(arow + j * 32);

    const int rbase = m0 + kb * 4;             // rows this lane's D covers
    float4 dv = make_float4(1.f, 1.f, 1.f, 1.f);
    if constexpr (SCALE) dv = *(const float4*)(dinv + rbase);
    const float ds[4] = {dv.x, dv.y, dv.z, dv.w};

#pragma unroll
    for (int nt = 0; nt < 4; nt++) {
        const int col = col0 + nt * 16 + l15;
        const _Float16* brow = Wt + (size_t)col * 128 + kb * 8;
        floatx4 acc = {0.f, 0.f, 0.f, 0.f};
#pragma unroll
        for (int j = 0; j < 4; j++) {
            half8 b = *(const half8*)(brow + j * 32);
            acc = __builtin_amdgcn_mfma_f32_16x16x32_f16(a[j], b, acc, 0, 0, 0);
        }
        if constexpr (HALF_OUT) {
            _Float16* Y = (_Float16*)Yv;
#pragma unroll
            for (int r = 0; r < 4; r++)
                Y[(size_t)(rbase + r) * OUT + col] = (_Float16)(acc[r] * ds[r]);
        } else {
            float* Y = (float*)Yv;
            float bc = ADD_BIAS ? bias[col] : 0.f;
#pragma unroll
            for (int r = 0; r < 4; r++)
                Y[(size_t)(rbase + r) * OUT + col] = acc[r] + bc;
        }
    }
}

// ---------------- fused aggregation ----------------
// t is dinv-pre-scaled fp16. out[c] = relu(dinv[c]*(t[c] + sum_src t[src]) + b), fp16.

__global__ __launch_bounds__(256)
void aggregate_h(const _Float16* __restrict__ t, const int* __restrict__ row_start,
                 const int* __restrict__ esrc, const float* __restrict__ dinv,
                 const float* __restrict__ bias, _Float16* __restrict__ out) {
    const int tid = threadIdx.x;
    const int node = blockIdx.x * 8 + (tid >> 5);
    const int f4 = tid & 31;   // features 4*f4 .. 4*f4+3
    if (node >= N_NODES) return;

    const int2* t2 = (const int2*)t;

    int2 sg = t2[(size_t)node * 32 + f4];       // self term (pre-scaled)
    float2 slo = __half22float2(*(__half2*)&sg.x);
    float2 shi = __half22float2(*(__half2*)&sg.y);
    float4 acc = make_float4(slo.x, slo.y, shi.x, shi.y);

    int k = row_start[node];
    const int k1 = row_start[node + 1];
    for (; k + 8 <= k1; k += 8) {
        int src[8];
#pragma unroll
        for (int u = 0; u < 8; u++) src[u] = esrc[k + u];
        int2 g[8];
#pragma unroll
        for (int u = 0; u < 8; u++) g[u] = t2[(size_t)src[u] * 32 + f4];
#pragma unroll
        for (int u = 0; u < 8; u++) {
            float2 lo = __half22float2(*(__half2*)&g[u].x);
            float2 hi = __half22float2(*(__half2*)&g[u].y);
            acc.x += lo.x;
            acc.y += lo.y;
            acc.z += hi.x;
            acc.w += hi.y;
        }
    }
    for (; k < k1; k++) {
        int2 g = t2[(size_t)esrc[k] * 32 + f4];
        float2 lo = __half22float2(*(__half2*)&g.x);
        float2 hi = __half22float2(*(__half2*)&g.y);
        acc.x += lo.x;
        acc.y += lo.y;
        acc.z += hi.x;
        acc.w += hi.y;
    }

    const float d = dinv[node];
    float4 b = ((const float4*)bias)[f4];
    acc.x = fmaxf(acc.x * d + b.x, 0.f);
    acc.y = fmaxf(acc.y * d + b.y, 0.f);
    acc.z = fmaxf(acc.z * d + b.z, 0.f);
    acc.w = fmaxf(acc.w * d + b.w, 0.f);

    union { __half2 h2[2]; int2 i2; } u;
    u.h2[0] = __floats2half2_rn(acc.x, acc.y);
    u.h2[1] = __floats2half2_rn(acc.z, acc.w);
    ((int2*)out)[(size_t)node * 32 + f4] = u.i2;
}

// ---------------- mean pool ----------------

__global__ __launch_bounds__(256)
void mean_partial(const float* __restrict__ P, float* __restrict__ sum) {
    __shared__ float red[256];
    const int tid = threadIdx.x;
    const int c = tid & 63;
    const int grp = tid >> 6;
    float acc = 0.0f;
    for (int r = blockIdx.x * 4 + grp; r < N_NODES; r += gridDim.x * 4)
        acc += P[r * OUT_CH + c];
    red[tid] = acc;
    __syncthreads();
    if (grp == 0) {
        float s = red[c] + red[64 + c] + red[128 + c] + red[192 + c];
        atomicAdd(&sum[c], s);
    }
}

__global__ void mean_final(const float* __restrict__ sum, float* __restrict__ out) {
    int j = threadIdx.x;
    if (j < OUT_CH) out[N_NODES * OUT_CH + j] = sum[j] * (1.0f / N_NODES);
}

// ---------------- launch ----------------

extern "C" void kernel_launch(void* const* d_in, const int* in_sizes, int n_in,
                              void* d_out, int out_size, void* d_ws, size_t ws_size,
                              hipStream_t stream) {
    const float* x  = (const float*)d_in[0];
    const int* ei   = (const int*)d_in[1];   // int32 on device
    const float* W1 = (const float*)d_in[2];
    const float* b1 = (const float*)d_in[3];
    const float* W2 = (const float*)d_in[4];
    const float* b2 = (const float*)d_in[5];
    const float* W3 = (const float*)d_in[6];
    const float* b3 = (const float*)d_in[7];
    const float* Wo = (const float*)d_in[8];
    const float* bo = (const float*)d_in[9];
    float* out = (float*)d_out;

    char* ws = (char*)d_ws;
    auto take = [&](size_t bytes) {
        char* p = ws;
        ws += (bytes + 255) & ~size_t(255);
        return (void*)p;
    };
    int*      counts    = (int*)take((size_t)N_NODES * 4);
    int*      row_start = (int*)take((size_t)(N_NODES + 1) * 4);
    int*      bsum      = (int*)take((size_t)NB_SCAN * 4);
    int*      cursor    = (int*)take((size_t)N_NODES * 4);
    float*    dinv      = (float*)take((size_t)N_NODES * 4);
    int*      esrc      = (int*)take((size_t)N_EDGES * 4);
    float*    sum       = (float*)take(OUT_CH * 4);
    _Float16* xh        = (_Float16*)take((size_t)N_NODES * HID * 2);
    _Float16* wt1       = (_Float16*)take((size_t)HID * HID * 2);
    _Float16* wt2       = (_Float16*)take((size_t)HID * HID * 2);
    _Float16* wt3       = (_Float16*)take((size_t)HID * HID * 2);
    _Float16* wto       = (_Float16*)take((size_t)HID * OUT_CH * 2);
    _Float16* hA        = (_Float16*)take((size_t)N_NODES * HID * 2);
    _Float16* hB        = (_Float16*)take((size_t)N_NODES * HID * 2);

    const int BS = 256;
    const int gN    = (N_NODES + BS - 1) / BS;
    const int gE    = (N_EDGES + BS - 1) / BS;
    const int gGemm = (N_NODES + 63) / 64;      // 782, n%16==0 so no partial bands
    const int gAgg  = (N_NODES + 7) / 8;
    const int gCvt  = (N_NODES * (HID / 4) + BS - 1) / BS;

    // CSR build
    prep_init<<<gN, BS, 0, stream>>>(counts, sum);
    count_edges<<<gE, BS, 0, stream>>>(ei, counts);
    scan_blocks<<<NB_SCAN, BS, 0, stream>>>(counts, row_start, bsum);
    scan_bsums<<<1, BS, 0, stream>>>(bsum);
    scan_fixup<<<gN, BS, 0, stream>>>(row_start, bsum, cursor, counts, dinv);
    csr_fill<<<gE, BS, 0, stream>>>(ei, cursor, esrc);

    // fp16 prep
    convert_x<<<gCvt, BS, 0, stream>>>(x, xh);
    wtrans<<<(HID * HID + BS - 1) / BS, BS, 0, stream>>>(W1, wt1, HID, HID);
    wtrans<<<(HID * HID + BS - 1) / BS, BS, 0, stream>>>(W2, wt2, HID, HID);
    wtrans<<<(HID * HID + BS - 1) / BS, BS, 0, stream>>>(W3, wt3, HID, HID);
    wtrans<<<(HID * OUT_CH + BS - 1) / BS, BS, 0, stream>>>(Wo, wto, HID, OUT_CH);

    const _Float16* hin = xh;
    const _Float16* wts[3] = {wt1, wt2, wt3};
    const float* bs[3] = {b1, b2, b3};
    for (int layer = 0; layer < 3; layer++) {
        gemm_mfma<HID, false, true, true><<<dim3(gGemm, 2), BS, 0, stream>>>(
            hin, wts[layer], nullptr, dinv, hA, N_NODES);
        aggregate_h<<<gAgg, BS, 0, stream>>>(hA, row_start, esrc, dinv, bs[layer], hB);
        hin = hB;
    }

    gemm_mfma<OUT_CH, true, false, false><<<dim3(gGemm, 1), BS, 0, stream>>>(
        hB, wto, bo, nullptr, out, N_NODES);
    mean_partial<<<256, BS, 0, stream>>>(out, sum);
    mean_final<<<1, 64, 0, stream>>>(sum, out);
}